// Round 7
// baseline (412.687 us; speedup 1.0000x reference)
//
#include <hip/hip_runtime.h>
#include <hip/hip_bf16.h>

// Problem constants
#define B_   4
#define NQ_  2048
#define NK_  2048
#define D_   1024
#define H_   16
#define DH_  64
#define SCALE_ 0.125f

typedef __attribute__((ext_vector_type(8))) __bf16 bf16x8;
typedef __attribute__((ext_vector_type(4))) float  f32x4;

typedef const __attribute__((address_space(1))) unsigned int* gas1p;
typedef __attribute__((address_space(3))) unsigned int*       las3p;

__device__ __forceinline__ f32x4 mfma16(bf16x8 a, bf16x8 b, f32x4 c) {
  return __builtin_amdgcn_mfma_f32_16x16x32_bf16(a, b, c, 0, 0, 0);
}
__device__ __forceinline__ void gload_lds16(const void* g, void* l) {
  __builtin_amdgcn_global_load_lds((gas1p)g, (las3p)l, 16, 0, 0);
}
__device__ __forceinline__ float nn_(float x) {
  if (__builtin_isnan(x)) return 0.0f;
  if (__builtin_isinf(x)) return x > 0.f ? 3.402823466e38f : -3.402823466e38f;
  return x;
}
__device__ __forceinline__ float exp2_(float x) {
#if __has_builtin(__builtin_amdgcn_exp2f)
  return __builtin_amdgcn_exp2f(x);
#else
  return __expf(x * 0.69314718056f);
#endif
}
__device__ __forceinline__ float fmax3_(float a, float b, float c) {
  return fmaxf(fmaxf(a, b), c);  // clang fuses to v_max3_f32
}

// ---------------- fp32 -> bf16 convert (vectorized) ----------------
__global__ __launch_bounds__(256) void cvt_bf16_k(const float* __restrict__ s,
                                                  __bf16* __restrict__ d, int n) {
  int i = (blockIdx.x * blockDim.x + threadIdx.x) << 2;
  if (i >= n) return;
  float4 v = *(const float4*)(s + i);
  __bf16 o[4] __attribute__((aligned(8))) = {(__bf16)v.x, (__bf16)v.y, (__bf16)v.z, (__bf16)v.w};
  *(uint2*)(d + i) = *(uint2*)o;
}

// ------------- weight transpose + convert + scale: src[K][N] -> dst[N][K] -------------
__global__ __launch_bounds__(256) void transpose_cvt_k(const float* __restrict__ src,
                                                       __bf16* __restrict__ dst,
                                                       int K, int N, float scale) {
  __shared__ float t[32][33];
  int n0 = blockIdx.x * 32, k0 = blockIdx.y * 32;
  int x = threadIdx.x, y0 = threadIdx.y;
  for (int yy = y0; yy < 32; yy += 8)
    t[yy][x] = src[(size_t)(k0 + yy) * N + n0 + x];
  __syncthreads();
  for (int yy = y0; yy < 32; yy += 8)
    dst[(size_t)(n0 + yy) * K + k0 + x] = (__bf16)(t[x][yy] * scale);
}

// ---------------- 3-buffer pipelined GEMM, fragment-order LDS ----------------
// BM=256, BN=128, BK=32, 512 threads = 8 waves (4M x 2N), per-wave 64x64 output.
// LDS holds each MFMA fragment as a contiguous 1KB block [fragid][lane][16B]:
// stage permutes the per-lane GLOBAL source so linear gload_lds dest = fragment order.
// ds_read_b128 then hits consecutive banks (ZERO conflicts) at base+imm offsets.
// 3 rotating buffers, tile t reads buf t%3 while staging t+2; counted vmcnt(3); 1 barrier/tile.
template <bool OUT_BF16, bool RES>
__global__ __launch_bounds__(512, 4) void gemm3p_k(const __bf16* __restrict__ A,
                                                   const __bf16* __restrict__ Bt,
                                                   const float* __restrict__ bias, float bscale,
                                                   const float* __restrict__ res,
                                                   void* __restrict__ out,
                                                   int M, int N, int K) {
  constexpr int BM = 256, BN = 128, BK = 32;
  __shared__ __attribute__((aligned(16))) __bf16 Al[3][BM * BK];  // 16KB each
  __shared__ __attribute__((aligned(16))) __bf16 Bl[3][BN * BK];  // 8KB each
  const int tid = threadIdx.x, lane = tid & 63, wid = tid >> 6;
  const int wr = wid >> 1, wc = wid & 1;
  const int g = lane >> 4, lr = lane & 15;
  const int m0 = blockIdx.y * BM, n0 = blockIdx.x * BN;

  // fragment-order staging: LDS chunk c holds A[row(c)][kcol(c)] where
  // row(c) = (c>>8)*64 + ((c>>6)&3)*16 + (c&15), kcol(c) = ((c>>4)&3)*8.
  const int cA0 = tid, cA1 = tid + 512, cB = tid;
  const int rA0 = ((cA0 >> 8) << 6) + (((cA0 >> 6) & 3) << 4) + (cA0 & 15);
  const int rA1 = ((cA1 >> 8) << 6) + (((cA1 >> 6) & 3) << 4) + (cA1 & 15);
  const int rB  = ((cB  >> 8) << 6) + (((cB  >> 6) & 3) << 4) + (cB  & 15);
  const __bf16* aS0 = A  + (size_t)(m0 + rA0) * K + (((cA0 >> 4) & 3) << 3);
  const __bf16* aS1 = A  + (size_t)(m0 + rA1) * K + (((cA1 >> 4) & 3) << 3);
  const __bf16* bS  = Bt + (size_t)(n0 + rB)  * K + (((cB  >> 4) & 3) << 3);
  char* aD0 = (char*)&Al[0][0] + (tid << 4);
  char* aD1 = aD0 + 8192;                      // chunk tid+512
  char* bD  = (char*)&Bl[0][0] + (tid << 4);

  const f32x4 zero4 = {0.f, 0.f, 0.f, 0.f};
  f32x4 acc[4][4];
#pragma unroll
  for (int m = 0; m < 4; m++)
#pragma unroll
    for (int n = 0; n < 4; n++) acc[m][n] = zero4;

  // prologue: stage tiles 0 and 1
  gload_lds16(aS0, aD0); gload_lds16(aS1, aD1); gload_lds16(bS, bD);
  gload_lds16(aS0 + BK, aD0 + 16384); gload_lds16(aS1 + BK, aD1 + 16384);
  gload_lds16(bS + BK, bD + 8192);
  aS0 += 2 * BK; aS1 += 2 * BK; bS += 2 * BK;
  asm volatile("s_waitcnt vmcnt(3)" ::: "memory");  // tile 0 landed (tile 1 in flight)
  __builtin_amdgcn_s_barrier();

  const int KT = K / BK;
  int cb = 0, b2 = 2;
  const int labase = lane << 4;
  for (int t = 0; t < KT; ++t) {
    const char* Ab = (const char*)&Al[0][0] + cb * 16384 + ((wr * 4) << 10) + labase;
    const char* Bb = (const char*)&Bl[0][0] + cb * 8192  + ((wc * 4) << 10) + labase;
    bf16x8 af[4], bv[4];
#pragma unroll
    for (int m = 0; m < 4; m++) af[m] = *(const bf16x8*)(Ab + (m << 10));
#pragma unroll
    for (int n = 0; n < 4; n++) bv[n] = *(const bf16x8*)(Bb + (n << 10));
    if (t < KT - 2) {  // stage tile t+2 (2 tiles from any reader -> race-free)
      gload_lds16(aS0, aD0 + b2 * 16384);
      gload_lds16(aS1, aD1 + b2 * 16384);
      gload_lds16(bS, bD + b2 * 8192);
      aS0 += BK; aS1 += BK; bS += BK;
    }
    __builtin_amdgcn_s_setprio(1);
#pragma unroll
    for (int m = 0; m < 4; m++)
#pragma unroll
      for (int n = 0; n < 4; n++) acc[m][n] = mfma16(af[m], bv[n], acc[m][n]);
    __builtin_amdgcn_s_setprio(0);
    if (t < KT - 2)       asm volatile("s_waitcnt vmcnt(3)" ::: "memory");  // t+1 landed
    else if (t == KT - 2) asm volatile("s_waitcnt vmcnt(0)" ::: "memory");
    if (t < KT - 1) __builtin_amdgcn_s_barrier();
    cb = (cb == 2) ? 0 : cb + 1;
    b2 = (b2 == 2) ? 0 : b2 + 1;
  }

  // epilogue: row = m0+wr*64+Mi*16+g*4+r ; col = n0+wc*64+Ni*16+lr
#pragma unroll
  for (int Mi = 0; Mi < 4; ++Mi) {
    int row = m0 + wr * 64 + Mi * 16 + g * 4;
#pragma unroll
    for (int Ni = 0; Ni < 4; ++Ni) {
      int col = n0 + wc * 64 + Ni * 16 + lr;
      float bvv = bias[col] * bscale;
#pragma unroll
      for (int r = 0; r < 4; ++r) {
        size_t idx = (size_t)(row + r) * N + col;
        float v = acc[Mi][Ni][r] + bvv;
        if (RES) v = nn_(v + res[idx]);
        if (OUT_BF16) ((__bf16*)out)[idx] = (__bf16)v;
        else          ((float*)out)[idx] = v;
      }
    }
  }
}

// ------------- per-head V transpose: KV_bf[B*NK][2048] -> Vt[(b*H+h)*64+d][NK] -------------
// Plain transpose (no swizzle needed: attention stages Vt in fragment order).
__global__ __launch_bounds__(256) void reorder_v_k(const __bf16* __restrict__ kv,
                                                   __bf16* __restrict__ vt) {
  __shared__ __attribute__((aligned(16))) __bf16 t[64][72];
  int bh = blockIdx.y, b = bh >> 4, h = bh & 15;
  int kk0 = blockIdx.x * 64;
  int tid = threadIdx.x;
#pragma unroll
  for (int i = 0; i < 2; i++) {
    int c = tid + i * 256;
    int kk = c >> 3, dc = c & 7;
    const __bf16* src = kv + (size_t)(b * NK_ + kk0 + kk) * 2048 + 1024 + h * 64 + dc * 8;
    *(float4*)&t[kk][dc * 8] = *(const float4*)src;
  }
  __syncthreads();
#pragma unroll
  for (int i = 0; i < 2; i++) {
    int c = tid + i * 256;
    int d = c >> 3, gch = c & 7;
    __bf16 tmp[8] __attribute__((aligned(16)));
#pragma unroll
    for (int j = 0; j < 8; j++) tmp[j] = t[gch * 8 + j][d];
    __bf16* dst = vt + ((size_t)bh * 64 + d) * (size_t)NK_ + kk0 + gch * 8;
    *(float4*)dst = *(float4*)tmp;
  }
}

// ---------------- flash attention: QBLK=32/wave, fragment-order K/V LDS ----------------
// grid 1024 blocks: bh=bid&63 (head->XCD pin), qblk=bid>>6. 4 waves x 32 q-rows = 128 q/block.
// K/V double-buffered in fragment order: frag f at [f*1024 + lane*16] -> conflict-free
// ds_read_b128, base+imm addressing, no swizzle VALU. K frag (n,ds); V frag (df,ks).
// Per tile: STAGE(next) -> vmcnt(4) -> barrier -> 2x{QK^T, online softmax, P roundtrip, PV}
// (sequential q-groups keep VGPR ~110) -> barrier. Q prescaled by SCALE*log2e.
__global__ __launch_bounds__(256) void attn_k(const __bf16* __restrict__ Qg,
                                              const __bf16* __restrict__ KVg,
                                              const __bf16* __restrict__ Vt,
                                              __bf16* __restrict__ AO) {
  __shared__ __attribute__((aligned(16))) __bf16 Kt[2][64 * 64];   // 8KB frag-order bufs
  __shared__ __attribute__((aligned(16))) __bf16 Vl[2][64 * 64];
  __shared__ __attribute__((aligned(16))) __bf16 Pl[4][32 * 64];   // 4KB per wave
  const int tid = threadIdx.x, lane = tid & 63, wid = tid >> 6;
  const int g = lane >> 4, lr = lane & 15;
  const int bid = blockIdx.x;
  const int bh = bid & 63, b = bh >> 4, h = bh & 15;
  const int qbase = (bid >> 6) * 128 + wid * 32;

  // Q fragments: q = qbase + qg*16 + lr, depth = ds*32 + g*8 .. +8
  bf16x8 qf[2][2];
#pragma unroll
  for (int qg = 0; qg < 2; ++qg) {
    const __bf16* qp = Qg + ((size_t)(b * NQ_ + qbase + qg * 16 + lr)) * 1024 + h * 64 + g * 8;
    qf[qg][0] = *(const bf16x8*)qp;
    qf[qg][1] = *(const bf16x8*)(qp + 32);
  }

  const f32x4 zero4 = {0.f, 0.f, 0.f, 0.f};
  f32x4 po[2][4];
#pragma unroll
  for (int qg = 0; qg < 2; ++qg)
#pragma unroll
    for (int df = 0; df < 4; df++) po[qg][df] = zero4;
  float m2[2] = {-1e30f, -1e30f}, l[2] = {0.f, 0.f};

  // P round-trip (per-wave buffer [32 q][64 k], XOR swizzle on lr&7 -> ~2-way)
  char* pw = (char*)&Pl[wid][0];
  const int pswz = (lr & 7) << 4;
  int wa[4], ra[2];
#pragma unroll
  for (int n = 0; n < 4; n++) wa[n] = lr * 128 + ((n * 32 + g * 8) ^ pswz);
#pragma unroll
  for (int ks = 0; ks < 2; ks++) ra[ks] = lr * 128 + ((ks * 64 + g * 16) ^ pswz);

  // fragment-order staging sources (running pointers, +const per tile)
  // K chunk c (0..511): frag = c>>6 = n*2+ds; row kk = ((c>>7)<<4)+(c&15);
  //                     col = ds*32 + ((c>>4)&3)*8
  const int cK0 = tid, cK1 = tid + 256;
  const int kk0r = ((cK0 >> 7) << 4) + (cK0 & 15), kk1r = ((cK1 >> 7) << 4) + (cK1 & 15);
  const int kc0 = (((cK0 >> 6) & 1) << 5) + (((cK0 >> 4) & 3) << 3);
  const int kc1 = (((cK1 >> 6) & 1) << 5) + (((cK1 >> 4) & 3) << 3);
  const __bf16* kp0 = KVg + (size_t)(b * NK_ + kk0r) * 2048 + h * 64 + kc0;
  const __bf16* kp1 = KVg + (size_t)(b * NK_ + kk1r) * 2048 + h * 64 + kc1;
  // V chunk c: frag = c>>6 = df*2+ks; d = ((c>>7)<<4)+(c&15); kcol = ks*32+((c>>4)&3)*8
  const int vd0 = ((cK0 >> 7) << 4) + (cK0 & 15), vd1 = ((cK1 >> 7) << 4) + (cK1 & 15);
  const __bf16* vp0 = Vt + (size_t)(bh * 64 + vd0) * NK_ + kc0;
  const __bf16* vp1 = Vt + (size_t)(bh * 64 + vd1) * NK_ + kc1;
  char* kD0 = (char*)&Kt[0][0] + (tid << 4);
  char* vD0 = (char*)&Vl[0][0] + (tid << 4);

#define STAGE_(bi)                                             \
  {                                                            \
    gload_lds16(kp0, kD0 + (bi) * 8192);                       \
    gload_lds16(kp1, kD0 + (bi) * 8192 + 4096);                \
    gload_lds16(vp0, vD0 + (bi) * 8192);                       \
    gload_lds16(vp1, vD0 + (bi) * 8192 + 4096);                \
    kp0 += 64 * 2048; kp1 += 64 * 2048; vp0 += 64; vp1 += 64;  \
  }

#define BODY_(bi)                                                                       \
  {                                                                                     \
    const char* Kb = (const char*)&Kt[bi][0] + (lane << 4);                             \
    const char* Vb = (const char*)&Vl[bi][0] + (lane << 4);                             \
    _Pragma("unroll") for (int qg = 0; qg < 2; ++qg) {                                  \
      f32x4 sa[4];                                                                      \
      __builtin_amdgcn_s_setprio(1);                                                    \
      _Pragma("unroll") for (int n = 0; n < 4; n++) {                                   \
        sa[n] = zero4;                                                                  \
        _Pragma("unroll") for (int ds = 0; ds < 2; ds++) {                              \
          bf16x8 kf = *(const bf16x8*)(Kb + ((n * 2 + ds) << 10));                      \
          sa[n] = mfma16(kf, qf[qg][ds], sa[n]);                                        \
        }                                                                               \
      }                                                                                 \
      __builtin_amdgcn_s_setprio(0);                                                    \
      float mx = fmax3_(sa[0][0], sa[0][1], sa[0][2]);                                  \
      mx = fmax3_(mx, sa[0][3], sa[1][0]);                                              \
      mx = fmax3_(mx, sa[1][1], sa[1][2]);                                              \
      mx = fmax3_(mx, sa[1][3], sa[2][0]);                                              \
      mx = fmax3_(mx, sa[2][1], sa[2][2]);                                              \
      mx = fmax3_(mx, sa[2][3], sa[3][0]);                                              \
      mx = fmax3_(mx, sa[3][1], sa[3][2]);                                              \
      mx = fmaxf(mx, sa[3][3]);                                                         \
      mx = fmaxf(mx, __shfl_xor(mx, 16));                                               \
      mx = fmaxf(mx, __shfl_xor(mx, 32));                                               \
      if (__any(mx > m2[qg] + 11.0f)) {                                                 \
        float mn = fmaxf(m2[qg], mx);                                                   \
        float alpha = exp2_(m2[qg] - mn);                                               \
        m2[qg] = mn;                                                                    \
        l[qg] *= alpha;                                                                 \
        _Pragma("unroll") for (int r = 0; r < 4; r++) {                                 \
          float ar = __shfl(alpha, g * 4 + r);                                          \
          _Pragma("unroll") for (int df = 0; df < 4; df++) po[qg][df][r] *= ar;         \
        }                                                                               \
      }                                                                                 \
      float rs = 0.f;                                                                   \
      _Pragma("unroll") for (int n = 0; n < 4; n++) {                                   \
        union { __bf16 hh[4]; uint2 u; } qd;                                            \
        _Pragma("unroll") for (int r = 0; r < 4; r++) {                                 \
          float p = exp2_(sa[n][r] - m2[qg]);                                           \
          rs += p;                                                                      \
          qd.hh[r] = (__bf16)p;                                                         \
        }                                                                               \
        *(uint2*)(pw + qg * 2048 + wa[n]) = qd.u;                                       \
      }                                                                                 \
      rs += __shfl_xor(rs, 16);                                                         \
      rs += __shfl_xor(rs, 32);                                                         \
      l[qg] += rs;                                                                      \
      bf16x8 pa[2];                                                                     \
      _Pragma("unroll") for (int ks = 0; ks < 2; ks++)                                  \
        pa[ks] = *(const bf16x8*)(pw + qg * 2048 + ra[ks]);                             \
      __builtin_amdgcn_s_setprio(1);                                                    \
      _Pragma("unroll") for (int df = 0; df < 4; df++) {                                \
        _Pragma("unroll") for (int ks = 0; ks < 2; ks++) {                              \
          bf16x8 vf = *(const bf16x8*)(Vb + ((df * 2 + ks) << 10));                     \
          po[qg][df] = mfma16(pa[ks], vf, po[qg][df]);                                  \
        }                                                                               \
      }                                                                                 \
      __builtin_amdgcn_s_setprio(0);                                                    \
    }                                                                                   \
  }

  STAGE_(0);  // tile 0 -> buf0

#pragma unroll 1
  for (int it = 0; it < 16; ++it) {
    STAGE_(1);
    asm volatile("s_waitcnt vmcnt(4)" ::: "memory");
    asm volatile("s_barrier" ::: "memory");
    BODY_(0);
    asm volatile("s_barrier" ::: "memory");
    if (it < 15) {
      STAGE_(0);
      asm volatile("s_waitcnt vmcnt(4)" ::: "memory");
    } else {
      asm volatile("s_waitcnt vmcnt(0)" ::: "memory");
    }
    asm volatile("s_barrier" ::: "memory");
    BODY_(1);
    asm volatile("s_barrier" ::: "memory");
  }

  // epilogue: O[q][d] / l ; po[qg][df][r]: q = qbase+qg*16+g*4+r, d = df*16+lr
#pragma unroll
  for (int qg = 0; qg < 2; ++qg) {
    float inv = 1.0f / l[qg];
#pragma unroll
    for (int r = 0; r < 4; r++) {
      float ir = __shfl(inv, g * 4 + r);
      size_t row = (size_t)(b * NQ_ + qbase + qg * 16 + g * 4 + r);
#pragma unroll
      for (int df = 0; df < 4; df++)
        AO[row * 1024 + h * 64 + df * 16 + lr] = (__bf16)(po[qg][df][r] * ir);
    }
  }
#undef STAGE_
#undef BODY_
}

extern "C" void kernel_launch(void* const* d_in, const int* in_sizes, int n_in,
                              void* d_out, int out_size, void* d_ws, size_t ws_size,
                              hipStream_t stream) {
  (void)in_sizes; (void)n_in; (void)out_size; (void)ws_size;
  const float* x_q  = (const float*)d_in[0];
  const float* x_kv = (const float*)d_in[1];
  const float* Wq   = (const float*)d_in[2];
  const float* bq   = (const float*)d_in[3];
  const float* Wkv  = (const float*)d_in[4];
  const float* bkv  = (const float*)d_in[5];
  const float* Wp   = (const float*)d_in[6];
  const float* bp   = (const float*)d_in[7];

  char* w = (char*)d_ws;
  __bf16* xq_bf  = (__bf16*)w; w += (size_t)8388608 * 2;   // [8192][1024]
  __bf16* xkv_bf = (__bf16*)w; w += (size_t)8388608 * 2;   // [8192][1024]
  __bf16* Wq_t   = (__bf16*)w; w += (size_t)1048576 * 2;   // [1024][1024]
  __bf16* Wkv_t  = (__bf16*)w; w += (size_t)2097152 * 2;   // [2048][1024]
  __bf16* Wp_t   = (__bf16*)w; w += (size_t)1048576 * 2;   // [1024][1024]
  __bf16* Q_bf   = (__bf16*)w; w += (size_t)8388608 * 2;   // [8192][1024]
  __bf16* KV_bf  = (__bf16*)w; w += (size_t)16777216 * 2;  // [8192][2048]
  __bf16* Vt     = (__bf16*)w; w += (size_t)8388608 * 2;   // [64*64][2048]
  __bf16* AO     = (__bf16*)w; w += (size_t)8388608 * 2;   // [8192][1024]

  const float C2 = SCALE_ * 1.44269504089f;  // fold softmax scale+log2e into Q projection

  cvt_bf16_k<<<8192, 256, 0, stream>>>(x_q, xq_bf, 8388608);
  cvt_bf16_k<<<8192, 256, 0, stream>>>(x_kv, xkv_bf, 8388608);
  transpose_cvt_k<<<dim3(32, 32), dim3(32, 8), 0, stream>>>(Wq, Wq_t, 1024, 1024, C2);
  transpose_cvt_k<<<dim3(64, 32), dim3(32, 8), 0, stream>>>(Wkv, Wkv_t, 1024, 2048, 1.0f);
  transpose_cvt_k<<<dim3(32, 32), dim3(32, 8), 0, stream>>>(Wp, Wp_t, 1024, 1024, 1.0f);

  gemm3p_k<true, false><<<dim3(8, 32), 512, 0, stream>>>(xq_bf, Wq_t, bq, C2, nullptr, Q_bf, 8192, 1024, 1024);
  gemm3p_k<true, false><<<dim3(16, 32), 512, 0, stream>>>(xkv_bf, Wkv_t, bkv, 1.0f, nullptr, KV_bf, 8192, 2048, 1024);
  reorder_v_k<<<dim3(32, 64), 256, 0, stream>>>(KV_bf, Vt);
  attn_k<<<1024, 256, 0, stream>>>(Q_bf, KV_bf, Vt, AO);
  gemm3p_k<false, true><<<dim3(8, 32), 512, 0, stream>>>(AO, Wp_t, bp, 1.0f, x_q, d_out, 8192, 1024, 1024);
}

// Round 8
// 388.864 us; speedup vs baseline: 1.0613x; 1.0613x over previous
//
#include <hip/hip_runtime.h>
#include <hip/hip_bf16.h>

// Problem constants
#define B_   4
#define NQ_  2048
#define NK_  2048
#define D_   1024
#define H_   16
#define DH_  64
#define SCALE_ 0.125f

typedef __attribute__((ext_vector_type(8))) __bf16 bf16x8;
typedef __attribute__((ext_vector_type(4))) float  f32x4;

typedef const __attribute__((address_space(1))) unsigned int* gas1p;
typedef __attribute__((address_space(3))) unsigned int*       las3p;

__device__ __forceinline__ f32x4 mfma16(bf16x8 a, bf16x8 b, f32x4 c) {
  return __builtin_amdgcn_mfma_f32_16x16x32_bf16(a, b, c, 0, 0, 0);
}
__device__ __forceinline__ void gload_lds16(const void* g, void* l) {
  __builtin_amdgcn_global_load_lds((gas1p)g, (las3p)l, 16, 0, 0);
}
__device__ __forceinline__ float nn_(float x) {
  if (__builtin_isnan(x)) return 0.0f;
  if (__builtin_isinf(x)) return x > 0.f ? 3.402823466e38f : -3.402823466e38f;
  return x;
}
__device__ __forceinline__ float exp2_(float x) {
#if __has_builtin(__builtin_amdgcn_exp2f)
  return __builtin_amdgcn_exp2f(x);
#else
  return __expf(x * 0.69314718056f);
#endif
}
__device__ __forceinline__ float fmax3_(float a, float b, float c) {
  return fmaxf(fmaxf(a, b), c);  // clang fuses to v_max3_f32
}

// ---------------- fp32 -> bf16 convert (vectorized) ----------------
__global__ __launch_bounds__(256) void cvt_bf16_k(const float* __restrict__ s,
                                                  __bf16* __restrict__ d, int n) {
  int i = (blockIdx.x * blockDim.x + threadIdx.x) << 2;
  if (i >= n) return;
  float4 v = *(const float4*)(s + i);
  __bf16 o[4] __attribute__((aligned(8))) = {(__bf16)v.x, (__bf16)v.y, (__bf16)v.z, (__bf16)v.w};
  *(uint2*)(d + i) = *(uint2*)o;
}

// ------------- weight transpose + convert + scale: src[K][N] -> dst[N][K] -------------
__global__ __launch_bounds__(256) void transpose_cvt_k(const float* __restrict__ src,
                                                       __bf16* __restrict__ dst,
                                                       int K, int N, float scale) {
  __shared__ float t[32][33];
  int n0 = blockIdx.x * 32, k0 = blockIdx.y * 32;
  int x = threadIdx.x, y0 = threadIdx.y;
  for (int yy = y0; yy < 32; yy += 8)
    t[yy][x] = src[(size_t)(k0 + yy) * N + n0 + x];
  __syncthreads();
  for (int yy = y0; yy < 32; yy += 8)
    dst[(size_t)(n0 + yy) * K + k0 + x] = (__bf16)(t[x][yy] * scale);
}

// ---------------- 3-buffer pipelined GEMM, fragment-order LDS, XCD-chunked grid ----------------
// BM=256, BN=128, BK=32, 512 threads = 8 waves (4M x 2N), per-wave 64x64 output.
// 1D grid with bijective XCD chunking: XCD j (= bid&7) owns wg in [j*G/8,(j+1)*G/8) ->
// 4 consecutive y-rows x all x-cols -> per-XCD working set ~4-6MB (A panels read once,
// B panels L2-resident). LDS in fragment order [fragid][lane][16B]: conflict-free
// ds_read_b128 at base+imm. 3 rotating buffers; counted vmcnt(3); ONE barrier/tile.
template <bool OUT_BF16, bool RES>
__global__ __launch_bounds__(512, 4) void gemm3p_k(const __bf16* __restrict__ A,
                                                   const __bf16* __restrict__ Bt,
                                                   const float* __restrict__ bias, float bscale,
                                                   const float* __restrict__ res,
                                                   void* __restrict__ out,
                                                   int M, int N, int K, int nX) {
  constexpr int BM = 256, BN = 128, BK = 32;
  __shared__ __attribute__((aligned(16))) __bf16 Al[3][BM * BK];  // 16KB each
  __shared__ __attribute__((aligned(16))) __bf16 Bl[3][BN * BK];  // 8KB each
  const int tid = threadIdx.x, lane = tid & 63, wid = tid >> 6;
  const int wr = wid >> 1, wc = wid & 1;
  const int g = lane >> 4, lr = lane & 15;

  // bijective XCD chunking (G divisible by 8)
  const int per = gridDim.x >> 3;
  const int wg = (blockIdx.x & 7) * per + (blockIdx.x >> 3);
  const int m0 = (wg / nX) * BM, n0 = (wg % nX) * BN;

  // fragment-order staging: LDS chunk c holds A[row(c)][kcol(c)] where
  // row(c) = (c>>8)*64 + ((c>>6)&3)*16 + (c&15), kcol(c) = ((c>>4)&3)*8.
  const int cA0 = tid, cA1 = tid + 512, cB = tid;
  const int rA0 = ((cA0 >> 8) << 6) + (((cA0 >> 6) & 3) << 4) + (cA0 & 15);
  const int rA1 = ((cA1 >> 8) << 6) + (((cA1 >> 6) & 3) << 4) + (cA1 & 15);
  const int rB  = ((cB  >> 8) << 6) + (((cB  >> 6) & 3) << 4) + (cB  & 15);
  const __bf16* aS0 = A  + (size_t)(m0 + rA0) * K + (((cA0 >> 4) & 3) << 3);
  const __bf16* aS1 = A  + (size_t)(m0 + rA1) * K + (((cA1 >> 4) & 3) << 3);
  const __bf16* bS  = Bt + (size_t)(n0 + rB)  * K + (((cB  >> 4) & 3) << 3);
  char* aD0 = (char*)&Al[0][0] + (tid << 4);
  char* aD1 = aD0 + 8192;                      // chunk tid+512
  char* bD  = (char*)&Bl[0][0] + (tid << 4);

  const f32x4 zero4 = {0.f, 0.f, 0.f, 0.f};
  f32x4 acc[4][4];
#pragma unroll
  for (int m = 0; m < 4; m++)
#pragma unroll
    for (int n = 0; n < 4; n++) acc[m][n] = zero4;

  // prologue: stage tiles 0 and 1
  gload_lds16(aS0, aD0); gload_lds16(aS1, aD1); gload_lds16(bS, bD);
  gload_lds16(aS0 + BK, aD0 + 16384); gload_lds16(aS1 + BK, aD1 + 16384);
  gload_lds16(bS + BK, bD + 8192);
  aS0 += 2 * BK; aS1 += 2 * BK; bS += 2 * BK;
  asm volatile("s_waitcnt vmcnt(3)" ::: "memory");  // tile 0 landed (tile 1 in flight)
  __builtin_amdgcn_s_barrier();

  const int KT = K / BK;
  int cb = 0, b2 = 2;
  const int labase = lane << 4;
  for (int t = 0; t < KT; ++t) {
    const char* Ab = (const char*)&Al[0][0] + cb * 16384 + ((wr * 4) << 10) + labase;
    const char* Bb = (const char*)&Bl[0][0] + cb * 8192  + ((wc * 4) << 10) + labase;
    bf16x8 af[4], bv[4];
#pragma unroll
    for (int m = 0; m < 4; m++) af[m] = *(const bf16x8*)(Ab + (m << 10));
#pragma unroll
    for (int n = 0; n < 4; n++) bv[n] = *(const bf16x8*)(Bb + (n << 10));
    if (t < KT - 2) {  // stage tile t+2 (2 tiles from any reader -> race-free)
      gload_lds16(aS0, aD0 + b2 * 16384);
      gload_lds16(aS1, aD1 + b2 * 16384);
      gload_lds16(bS, bD + b2 * 8192);
      aS0 += BK; aS1 += BK; bS += BK;
    }
    __builtin_amdgcn_s_setprio(1);
#pragma unroll
    for (int m = 0; m < 4; m++)
#pragma unroll
      for (int n = 0; n < 4; n++) acc[m][n] = mfma16(af[m], bv[n], acc[m][n]);
    __builtin_amdgcn_s_setprio(0);
    if (t < KT - 2)       asm volatile("s_waitcnt vmcnt(3)" ::: "memory");  // t+1 landed
    else if (t == KT - 2) asm volatile("s_waitcnt vmcnt(0)" ::: "memory");
    if (t < KT - 1) __builtin_amdgcn_s_barrier();
    cb = (cb == 2) ? 0 : cb + 1;
    b2 = (b2 == 2) ? 0 : b2 + 1;
  }

  // epilogue: row = m0+wr*64+Mi*16+g*4+r ; col = n0+wc*64+Ni*16+lr
#pragma unroll
  for (int Mi = 0; Mi < 4; ++Mi) {
    int row = m0 + wr * 64 + Mi * 16 + g * 4;
#pragma unroll
    for (int Ni = 0; Ni < 4; ++Ni) {
      int col = n0 + wc * 64 + Ni * 16 + lr;
      float bvv = bias[col] * bscale;
#pragma unroll
      for (int r = 0; r < 4; ++r) {
        size_t idx = (size_t)(row + r) * N + col;
        float v = acc[Mi][Ni][r] + bvv;
        if (RES) v = nn_(v + res[idx]);
        if (OUT_BF16) ((__bf16*)out)[idx] = (__bf16)v;
        else          ((float*)out)[idx] = v;
      }
    }
  }
}

// ------------- per-head V transpose: KV_bf[B*NK][2048] -> Vt[(b*H+h)*64+d][NK] -------------
// Vt rows chunk-swizzled per 128B tile-segment: chunk g holds source kk-chunk g^(d&7),
// so attention stages linearly with gload_lds and reads swizzled (rule #21).
__global__ __launch_bounds__(256) void reorder_v_k(const __bf16* __restrict__ kv,
                                                   __bf16* __restrict__ vt) {
  __shared__ __attribute__((aligned(16))) __bf16 t[64][72];
  int bh = blockIdx.y, b = bh >> 4, h = bh & 15;
  int kk0 = blockIdx.x * 64;
  int tid = threadIdx.x;
#pragma unroll
  for (int i = 0; i < 2; i++) {
    int c = tid + i * 256;
    int kk = c >> 3, dc = c & 7;
    const __bf16* src = kv + (size_t)(b * NK_ + kk0 + kk) * 2048 + 1024 + h * 64 + dc * 8;
    *(float4*)&t[kk][dc * 8] = *(const float4*)src;
  }
  __syncthreads();
#pragma unroll
  for (int i = 0; i < 2; i++) {
    int c = tid + i * 256;
    int d = c >> 3, gch = c & 7;
    int s = gch ^ (d & 7);
    __bf16 tmp[8] __attribute__((aligned(16)));
#pragma unroll
    for (int j = 0; j < 8; j++) tmp[j] = t[s * 8 + j][d];
    __bf16* dst = vt + ((size_t)bh * 64 + d) * (size_t)NK_ + kk0 + gch * 8;
    *(float4*)dst = *(float4*)tmp;
  }
}

// ---------------- flash attention (round-6 best: 134.5us): staged LDS + swapped QK^T ----------
// 1D grid 2048 blocks: bh=bid&63 (head->XCD pinning). 4 waves x 16 q-rows, KVBLK=64,
// K/V double-buffered. Per tile: STAGE(next,ptr+=const) -> vmcnt(4) -> barrier -> QK^T ->
// softmax(max3 tree) -> P round-trip -> PV -> barrier. 2-tile unroll; running pointers.
// Q prescaled by SCALE*log2e at projection.
__global__ __launch_bounds__(256) void attn_k(const __bf16* __restrict__ Qg,
                                              const __bf16* __restrict__ KVg,
                                              const __bf16* __restrict__ Vt,
                                              __bf16* __restrict__ AO) {
  __shared__ __attribute__((aligned(16))) __bf16 Kt[2][64 * 64];
  __shared__ __attribute__((aligned(16))) __bf16 Vl[2][64 * 64];
  __shared__ __attribute__((aligned(16))) __bf16 Pl[4][16 * 64];
  const int tid = threadIdx.x, lane = tid & 63, wid = tid >> 6;
  const int g = lane >> 4, lr = lane & 15;
  const int bid = blockIdx.x;
  const int bh = bid & 63, b = bh >> 4, h = bh & 15;
  const int qbase = (bid >> 6) * 64 + wid * 16;

  bf16x8 qf[2];
  {
    const __bf16* qp = Qg + ((size_t)(b * NQ_ + qbase + lr)) * 1024 + h * 64 + g * 8;
    qf[0] = *(const bf16x8*)qp;
    qf[1] = *(const bf16x8*)(qp + 32);
  }

  const f32x4 zero4 = {0.f, 0.f, 0.f, 0.f};
  f32x4 po[4];
#pragma unroll
  for (int df = 0; df < 4; df++) po[df] = zero4;
  float m2 = -1e30f, l = 0.f;

  char* pw = (char*)&Pl[wid][0];
  const int pswz = (lr & 7) << 4;
  int wa[4], ra[2];
#pragma unroll
  for (int n = 0; n < 4; n++) wa[n] = lr * 128 + ((n * 32 + g * 8) ^ pswz);
#pragma unroll
  for (int ks = 0; ks < 2; ks++) ra[ks] = lr * 128 + ((ks * 64 + g * 16) ^ pswz);

  // running staging pointers (advance by constant stride per tile)
  const int kk = wid * 16 + (lane >> 3);
  const int cc = lane & 7;
  const __bf16* kp0 = KVg + (size_t)b * NK_ * 2048 + h * 64 + (size_t)kk * 2048 + ((cc ^ (kk & 7)) << 3);
  const __bf16* kp1 = kp0 + 8 * 2048;        // (kk+8)&7 == kk&7 -> same swizzle
  const __bf16* vp0 = Vt + (size_t)bh * 64 * (size_t)NK_ + (size_t)kk * NK_ + (cc << 3);
  const __bf16* vp1 = vp0 + 8 * NK_;
  char* kd0 = (char*)&Kt[0][0] + wid * 2048;
  char* vd0 = (char*)&Vl[0][0] + wid * 2048;

#define STAGE_(bi)                                             \
  {                                                            \
    gload_lds16(kp0, kd0 + (bi) * 8192);                       \
    gload_lds16(kp1, kd0 + (bi) * 8192 + 1024);                \
    gload_lds16(vp0, vd0 + (bi) * 8192);                       \
    gload_lds16(vp1, vd0 + (bi) * 8192 + 1024);                \
    kp0 += 64 * 2048; kp1 += 64 * 2048; vp0 += 64; vp1 += 64;  \
  }

#define BODY_(bi)                                                                              \
  {                                                                                            \
    const char* Kb = (const char*)&Kt[bi][0];                                                  \
    const char* Vb = (const char*)&Vl[bi][0];                                                  \
    f32x4 sa[4];                                                                               \
    __builtin_amdgcn_s_setprio(1);                                                             \
    _Pragma("unroll") for (int n = 0; n < 4; n++) {                                            \
      sa[n] = zero4;                                                                           \
      int kr = n * 16 + lr;                                                                    \
      _Pragma("unroll") for (int ds = 0; ds < 2; ds++) {                                       \
        bf16x8 kf = *(const bf16x8*)(Kb + kr * 128 + ((ds * 64 + g * 16) ^ ((kr & 7) << 4)));  \
        sa[n] = mfma16(kf, qf[ds], sa[n]);                                                     \
      }                                                                                        \
    }                                                                                          \
    __builtin_amdgcn_s_setprio(0);                                                             \
    float mx = fmax3_(sa[0][0], sa[0][1], sa[0][2]);                                           \
    mx = fmax3_(mx, sa[0][3], sa[1][0]);                                                       \
    mx = fmax3_(mx, sa[1][1], sa[1][2]);                                                       \
    mx = fmax3_(mx, sa[1][3], sa[2][0]);                                                       \
    mx = fmax3_(mx, sa[2][1], sa[2][2]);                                                       \
    mx = fmax3_(mx, sa[2][3], sa[3][0]);                                                       \
    mx = fmax3_(mx, sa[3][1], sa[3][2]);                                                       \
    mx = fmaxf(mx, sa[3][3]);                                                                  \
    mx = fmaxf(mx, __shfl_xor(mx, 16));                                                        \
    mx = fmaxf(mx, __shfl_xor(mx, 32));                                                        \
    if (__any(mx > m2 + 11.0f)) {                                                              \
      float mn = fmaxf(m2, mx);                                                                \
      float alpha = exp2_(m2 - mn);                                                            \
      m2 = mn;                                                                                 \
      l *= alpha;                                                                              \
      _Pragma("unroll") for (int r = 0; r < 4; r++) {                                          \
        float ar = __shfl(alpha, g * 4 + r);                                                   \
        _Pragma("unroll") for (int df = 0; df < 4; df++) po[df][r] *= ar;                      \
      }                                                                                        \
    }                                                                                          \
    float rs = 0.f;                                                                            \
    _Pragma("unroll") for (int n = 0; n < 4; n++) {                                            \
      union { __bf16 hh[4]; uint2 u; } qd;                                                     \
      _Pragma("unroll") for (int r = 0; r < 4; r++) {                                          \
        float p = exp2_(sa[n][r] - m2);                                                        \
        rs += p;                                                                               \
        qd.hh[r] = (__bf16)p;                                                                  \
      }                                                                                        \
      *(uint2*)(pw + wa[n]) = qd.u;                                                            \
    }                                                                                          \
    rs += __shfl_xor(rs, 16);                                                                  \
    rs += __shfl_xor(rs, 32);                                                                  \
    l += rs;                                                                                   \
    bf16x8 pa[2];                                                                              \
    _Pragma("unroll") for (int ks = 0; ks < 2; ks++)                                           \
      pa[ks] = *(const bf16x8*)(pw + ra[ks]);                                                  \
    __builtin_amdgcn_s_setprio(1);                                                             \
    _Pragma("unroll") for (int df = 0; df < 4; df++) {                                         \
      int d = df * 16 + lr;                                                                    \
      _Pragma("unroll") for (int ks = 0; ks < 2; ks++) {                                       \
        bf16x8 vf = *(const bf16x8*)(Vb + d * 128 + ((ks * 64 + g * 16) ^ ((d & 7) << 4)));    \
        po[df] = mfma16(pa[ks], vf, po[df]);                                                   \
      }                                                                                        \
    }                                                                                          \
    __builtin_amdgcn_s_setprio(0);                                                             \
  }

  STAGE_(0);  // tile 0 -> buf0

#pragma unroll 1
  for (int it = 0; it < 16; ++it) {
    STAGE_(1);
    asm volatile("s_waitcnt vmcnt(4)" ::: "memory");
    asm volatile("s_barrier" ::: "memory");
    BODY_(0);
    asm volatile("s_barrier" ::: "memory");
    if (it < 15) {
      STAGE_(0);
      asm volatile("s_waitcnt vmcnt(4)" ::: "memory");
    } else {
      asm volatile("s_waitcnt vmcnt(0)" ::: "memory");
    }
    asm volatile("s_barrier" ::: "memory");
    BODY_(1);
    asm volatile("s_barrier" ::: "memory");
  }

  float inv = 1.0f / l;
#pragma unroll
  for (int r = 0; r < 4; r++) {
    float ir = __shfl(inv, g * 4 + r);
    size_t row = (size_t)(b * NQ_ + qbase + g * 4 + r);
#pragma unroll
    for (int df = 0; df < 4; df++)
      AO[row * 1024 + h * 64 + df * 16 + lr] = (__bf16)(po[df][r] * ir);
  }
#undef STAGE_
#undef BODY_
}

extern "C" void kernel_launch(void* const* d_in, const int* in_sizes, int n_in,
                              void* d_out, int out_size, void* d_ws, size_t ws_size,
                              hipStream_t stream) {
  (void)in_sizes; (void)n_in; (void)out_size; (void)ws_size;
  const float* x_q  = (const float*)d_in[0];
  const float* x_kv = (const float*)d_in[1];
  const float* Wq   = (const float*)d_in[2];
  const float* bq   = (const float*)d_in[3];
  const float* Wkv  = (const float*)d_in[4];
  const float* bkv  = (const float*)d_in[5];
  const float* Wp   = (const float*)d_in[6];
  const float* bp   = (const float*)d_in[7];

  char* w = (char*)d_ws;
  __bf16* xq_bf  = (__bf16*)w; w += (size_t)8388608 * 2;   // [8192][1024]
  __bf16* xkv_bf = (__bf16*)w; w += (size_t)8388608 * 2;   // [8192][1024]
  __bf16* Wq_t   = (__bf16*)w; w += (size_t)1048576 * 2;   // [1024][1024]
  __bf16* Wkv_t  = (__bf16*)w; w += (size_t)2097152 * 2;   // [2048][1024]
  __bf16* Wp_t   = (__bf16*)w; w += (size_t)1048576 * 2;   // [1024][1024]
  __bf16* Q_bf   = (__bf16*)w; w += (size_t)8388608 * 2;   // [8192][1024]
  __bf16* KV_bf  = (__bf16*)w; w += (size_t)16777216 * 2;  // [8192][2048]
  __bf16* Vt     = (__bf16*)w; w += (size_t)8388608 * 2;   // [64*64][2048]
  __bf16* AO     = (__bf16*)w; w += (size_t)8388608 * 2;   // [8192][1024]

  const float C2 = SCALE_ * 1.44269504089f;  // fold softmax scale+log2e into Q projection

  cvt_bf16_k<<<8192, 256, 0, stream>>>(x_q, xq_bf, 8388608);
  cvt_bf16_k<<<8192, 256, 0, stream>>>(x_kv, xkv_bf, 8388608);
  transpose_cvt_k<<<dim3(32, 32), dim3(32, 8), 0, stream>>>(Wq, Wq_t, 1024, 1024, C2);
  transpose_cvt_k<<<dim3(64, 32), dim3(32, 8), 0, stream>>>(Wkv, Wkv_t, 1024, 2048, 1.0f);
  transpose_cvt_k<<<dim3(32, 32), dim3(32, 8), 0, stream>>>(Wp, Wp_t, 1024, 1024, 1.0f);

  gemm3p_k<true, false><<<256, 512, 0, stream>>>(xq_bf, Wq_t, bq, C2, nullptr, Q_bf, 8192, 1024, 1024, 8);
  gemm3p_k<true, false><<<512, 512, 0, stream>>>(xkv_bf, Wkv_t, bkv, 1.0f, nullptr, KV_bf, 8192, 2048, 1024, 16);
  reorder_v_k<<<dim3(32, 64), 256, 0, stream>>>(KV_bf, Vt);
  attn_k<<<2048, 256, 0, stream>>>(Q_bf, KV_bf, Vt, AO);
  gemm3p_k<false, true><<<256, 512, 0, stream>>>(AO, Wp_t, bp, 1.0f, x_q, d_out, 8192, 1024, 1024, 8);
}